// Round 6
// baseline (382.923 us; speedup 1.0000x reference)
//
#include <hip/hip_runtime.h>
#include <cfloat>
#include <cstdint>

#define NPTS 65536
#define DIM 256
#define NC 16
#define KSEL 2048
#define SORT_M 8192
#define EPSV 1e-6f

// ws layout (bytes):
//     0 : float sums[16*256]   (16384)
// 16384 : int counts[16]       (64)
// 16448 : int cursors[16]      (64)
// 16512 : int offsets[16]      (64)
// 16576 : float csq[16]        (64)
// 16640 : float pos_stat[16]   (64)
// 16704 : float neg_stat[256]  (1024)
// 17728 : float centers[4096]  (16384)
// 65536 : float Dmat[16*65536] (4 MB)

__global__ void __launch_bounds__(256) k_accum(const float* __restrict__ x,
                                               const int* __restrict__ y,
                                               float* __restrict__ gsums,
                                               int* __restrict__ gcounts) {
  __shared__ float lsum[NC * DIM];
  __shared__ int lcnt[NC];
  int tid = threadIdx.x;  // = dim
  for (int j = tid; j < NC * DIM; j += 256) lsum[j] = 0.f;
  if (tid < NC) lcnt[tid] = 0;
  __syncthreads();
  int n0 = blockIdx.x * 64;
  for (int r = 0; r < 64; ++r) {
    int n = n0 + r;
    int lab = y[n * 3 + 2];
    lsum[lab * DIM + tid] += x[(size_t)n * DIM + tid];
    if (tid == 0) lcnt[lab]++;
  }
  __syncthreads();
  for (int c = 0; c < NC; ++c)
    atomicAdd(&gsums[c * DIM + tid], lsum[c * DIM + tid]);
  if (tid < NC) atomicAdd(&gcounts[tid], lcnt[tid]);
}

__global__ void __launch_bounds__(256) k_centers(const float* __restrict__ gsums,
                                                 const int* __restrict__ gcounts,
                                                 float* __restrict__ centers,
                                                 float* __restrict__ csq,
                                                 int* __restrict__ offsets) {
  __shared__ float red[DIM];
  int d = threadIdx.x;
  float v[NC];
#pragma unroll
  for (int c = 0; c < NC; ++c) {
    v[c] = gsums[c * DIM + d] / (float)gcounts[c] + EPSV;
    centers[c * DIM + d] = v[c];
  }
#pragma unroll 1
  for (int c = 0; c < NC; ++c) {
    red[d] = v[c] * v[c];
    __syncthreads();
    for (int st = 128; st > 0; st >>= 1) {
      if (d < st) red[d] += red[d + st];
      __syncthreads();
    }
    if (d == 0) csq[c] = red[0];
    __syncthreads();
  }
  if (d == 0) {
    int run = 0;
    for (int c = 0; c < NC; ++c) { offsets[c] = run; run += gcounts[c]; }
  }
}

// 8 threads per point: s = lane&7 owns dims [s*32, s*32+32). Grid 2048 blocks
// -> 8 blocks/CU -> 32 waves/CU (occupancy fix vs. 256-block version).
// Centers in LDS with XOR swizzle so the (same-class, q=s*8+j) read pattern
// lands on banks 4*(j^s): conflict-free (same-addr lanes broadcast).
__global__ void __launch_bounds__(256) k_dist(const float* __restrict__ x,
                                              const int* __restrict__ y,
                                              const float* __restrict__ centers,
                                              const float* __restrict__ csq,
                                              const int* __restrict__ offsets,
                                              int* __restrict__ cursors,
                                              float* __restrict__ Dmat) {
  __shared__ float4 cc[NC * 64];  // swizzled: (i,q) stored at i*64 + swz(q)
  __shared__ float csql[NC];
  int t = threadIdx.x;
  const float4* cptr = (const float4*)centers;
  for (int u = t; u < NC * 64; u += 256) {
    int q = u & 63;
    int qs = (q & 0x38) | ((q & 7) ^ ((q >> 3) & 7));
    cc[(u & ~63) | qs] = cptr[u];
  }
  if (t < NC) csql[t] = csq[t];
  __syncthreads();

  int g = blockIdx.x * 256 + t;
  int p = g >> 3;       // point
  int s = g & 7;        // dim-chunk: dims [s*32, s*32+32)
  const float4* xp = (const float4*)(x + (size_t)p * DIM) + s * 8;
  float4 xv[8];
#pragma unroll
  for (int j = 0; j < 8; ++j) xv[j] = xp[j];
  float xsq = 0.f;
#pragma unroll
  for (int j = 0; j < 8; ++j)
    xsq += xv[j].x * xv[j].x + xv[j].y * xv[j].y + xv[j].z * xv[j].z + xv[j].w * xv[j].w;

  float acc[NC];
#pragma unroll
  for (int i = 0; i < NC; ++i) acc[i] = 0.f;
#pragma unroll
  for (int i = 0; i < NC; ++i) {
#pragma unroll
    for (int j = 0; j < 8; ++j) {
      float4 cv = cc[i * 64 + s * 8 + (j ^ s)];  // element (i, q=s*8+j)
      acc[i] += xv[j].x * cv.x + xv[j].y * cv.y + xv[j].z * cv.z + xv[j].w * cv.w;
    }
  }

  // reduce partials across the 8 lanes of this point
#pragma unroll
  for (int m = 1; m < 8; m <<= 1) {
    xsq += __shfl_xor(xsq, m);
#pragma unroll
    for (int i = 0; i < NC; ++i) acc[i] += __shfl_xor(acc[i], m);
  }

  if (s == 0) {
    int lab = y[p * 3 + 2];
    int slot = atomicAdd(&cursors[lab], 1);
    int base = offsets[lab] + slot;
#pragma unroll
    for (int i = 0; i < NC; ++i) {
      float d2 = csql[i] - 2.f * acc[i] + xsq;
      Dmat[(size_t)i * NPTS + base] = sqrtf(fmaxf(d2, 0.f));
    }
  }
}

__global__ void __launch_bounds__(512) k_select(const float* __restrict__ Dmat,
                                                const int* __restrict__ gcounts,
                                                const int* __restrict__ offsets,
                                                float* __restrict__ pos_stat,
                                                float* __restrict__ neg_stat) {
  __shared__ float s[SORT_M];
  __shared__ float red[512];
  int tid = threadIdx.x;
  int b = blockIdx.x;
  int ci = b >> 4;  // center index i
  int cl = b & 15;  // class index c
  int cnt = gcounts[cl];
  int off = offsets[cl];
  const float* src = Dmat + (size_t)ci * NPTS + off;
  for (int t = tid; t < SORT_M; t += 512) s[t] = (t < cnt) ? src[t] : FLT_MAX;
  __syncthreads();

  for (int k = 2; k <= SORT_M; k <<= 1) {
    for (int j = k >> 1; j > 0; j >>= 1) {
      for (int p = tid; p < SORT_M / 2; p += 512) {
        int i = ((p & ~(j - 1)) << 1) | (p & (j - 1));
        int ixj = i | j;
        bool up = ((i & k) == 0);
        float a = s[i], bb = s[ixj];
        if ((a > bb) == up) { s[i] = bb; s[ixj] = a; }
      }
      __syncthreads();
    }
  }

  // --- neg stats: K smallest = s[0..KSEL) ---
  float part = 0.f;
  for (int t = tid; t < KSEL; t += 512) part += s[t];
  red[tid] = part; __syncthreads();
  for (int st = 256; st > 0; st >>= 1) { if (tid < st) red[tid] += red[tid + st]; __syncthreads(); }
  float mean = red[0] / (float)KSEL;
  __syncthreads();
  part = 0.f;
  for (int t = tid; t < KSEL; t += 512) { float dd = s[t] - mean; part += dd * dd; }
  red[tid] = part; __syncthreads();
  for (int st = 256; st > 0; st >>= 1) { if (tid < st) red[tid] += red[tid + st]; __syncthreads(); }
  if (tid == 0) {
    float var = red[0] / (float)(KSEL - 1);
    neg_stat[ci * 16 + cl] = mean - 1.96f * sqrtf(var);
  }

  // --- pos stats (only diagonal): K largest = s[cnt-KSEL..cnt) ---
  if (ci == cl) {
    __syncthreads();
    part = 0.f;
    for (int t = tid; t < KSEL; t += 512) part += s[cnt - KSEL + t];
    red[tid] = part; __syncthreads();
    for (int st = 256; st > 0; st >>= 1) { if (tid < st) red[tid] += red[tid + st]; __syncthreads(); }
    float pm = red[0] / (float)KSEL;
    __syncthreads();
    part = 0.f;
    for (int t = tid; t < KSEL; t += 512) { float dd = s[cnt - KSEL + t] - pm; part += dd * dd; }
    red[tid] = part; __syncthreads();
    for (int st = 256; st > 0; st >>= 1) { if (tid < st) red[tid] += red[tid + st]; __syncthreads(); }
    if (tid == 0) {
      float var = red[0] / (float)(KSEL - 1);
      pos_stat[ci] = pm + 1.96f * sqrtf(var);
    }
  }
}

__global__ void __launch_bounds__(256) k_loss(const float* __restrict__ pos_stat,
                                              const float* __restrict__ neg_stat,
                                              float* __restrict__ out) {
  __shared__ float red[256];
  int t = threadIdx.x;
  int i = t >> 4, c = t & 15;
  float v = 0.f;
  if (i != c) v = fmaxf(1.0f + pos_stat[i] - neg_stat[t], 0.f);
  red[t] = v; __syncthreads();
  for (int st = 128; st > 0; st >>= 1) { if (t < st) red[t] += red[t + st]; __syncthreads(); }
  if (t == 0) out[0] = red[0];
}

extern "C" void kernel_launch(void* const* d_in, const int* in_sizes, int n_in,
                              void* d_out, int out_size, void* d_ws, size_t ws_size,
                              hipStream_t stream) {
  const float* x = (const float*)d_in[0];
  const int* y = (const int*)d_in[1];
  float* out = (float*)d_out;
  char* ws = (char*)d_ws;

  float* sums = (float*)(ws + 0);
  int* counts = (int*)(ws + 16384);
  int* cursors = (int*)(ws + 16448);
  int* offsets = (int*)(ws + 16512);
  float* csq = (float*)(ws + 16576);
  float* pos_stat = (float*)(ws + 16640);
  float* neg_stat = (float*)(ws + 16704);
  float* centers = (float*)(ws + 17728);
  float* Dmat = (float*)(ws + 65536);

  hipMemsetAsync(ws, 0, 16512, stream);  // sums + counts + cursors
  k_accum<<<1024, 256, 0, stream>>>(x, y, sums, counts);
  k_centers<<<1, 256, 0, stream>>>(sums, counts, centers, csq, offsets);
  k_dist<<<2048, 256, 0, stream>>>(x, y, centers, csq, offsets, cursors, Dmat);
  k_select<<<256, 512, 0, stream>>>(Dmat, counts, offsets, pos_stat, neg_stat);
  k_loss<<<1, 256, 0, stream>>>(pos_stat, neg_stat, out);
}

// Round 8
// 203.608 us; speedup vs baseline: 1.8807x; 1.8807x over previous
//
#include <hip/hip_runtime.h>
#include <cfloat>
#include <cstdint>

#define NPTS 65536
#define DIM 256
#define NC 16
#define KSEL 2048
#define SORT_M 8192
#define EPSV 1e-6f

// ws layout (bytes):
//     0 : float sums[16*256]   (16384)
// 16384 : int counts[16]       (64)
// 16448 : (unused)
// 16512 : int offsets[16]      (64)
// 16576 : float csq[16]        (64)
// 16640 : float pos_stat[16]   (64)
// 16704 : float neg_stat[256]  (1024)
// 17728 : float centers[4096]  (16384)
// 34112 : int bhist[256*16]    (16384)  -- per-chunk class histogram -> scanned bases
// 65536 : float Dmat[16*65536] (4 MB)

__global__ void __launch_bounds__(256) k_accum(const float* __restrict__ x,
                                               const int* __restrict__ y,
                                               float* __restrict__ gsums,
                                               int* __restrict__ gcounts) {
  __shared__ float lsum[NC * DIM];
  __shared__ int lcnt[NC];
  int tid = threadIdx.x;  // = dim
  for (int j = tid; j < NC * DIM; j += 256) lsum[j] = 0.f;
  if (tid < NC) lcnt[tid] = 0;
  __syncthreads();
  int n0 = blockIdx.x * 64;
  for (int r = 0; r < 64; ++r) {
    int n = n0 + r;
    int lab = y[n * 3 + 2];
    lsum[lab * DIM + tid] += x[(size_t)n * DIM + tid];
    if (tid == 0) lcnt[lab]++;
  }
  __syncthreads();
  for (int c = 0; c < NC; ++c)
    atomicAdd(&gsums[c * DIM + tid], lsum[c * DIM + tid]);
  if (tid < NC) atomicAdd(&gcounts[tid], lcnt[tid]);
}

__global__ void __launch_bounds__(256) k_centers(const float* __restrict__ gsums,
                                                 const int* __restrict__ gcounts,
                                                 float* __restrict__ centers,
                                                 float* __restrict__ csq,
                                                 int* __restrict__ offsets) {
  __shared__ float red[DIM];
  int d = threadIdx.x;
  float v[NC];
#pragma unroll
  for (int c = 0; c < NC; ++c) {
    v[c] = gsums[c * DIM + d] / (float)gcounts[c] + EPSV;
    centers[c * DIM + d] = v[c];
  }
#pragma unroll 1
  for (int c = 0; c < NC; ++c) {
    red[d] = v[c] * v[c];
    __syncthreads();
    for (int st = 128; st > 0; st >>= 1) {
      if (d < st) red[d] += red[d + st];
      __syncthreads();
    }
    if (d == 0) csq[c] = red[0];
    __syncthreads();
  }
  if (d == 0) {
    int run = 0;
    for (int c = 0; c < NC; ++c) { offsets[c] = run; run += gcounts[c]; }
  }
}

// Per-chunk (256 points) class histogram.
__global__ void __launch_bounds__(256) k_hist(const int* __restrict__ y,
                                              int* __restrict__ bhist) {
  __shared__ int h[NC];
  int t = threadIdx.x;
  if (t < NC) h[t] = 0;
  __syncthreads();
  int p = blockIdx.x * 256 + t;
  atomicAdd(&h[y[p * 3 + 2]], 1);
  __syncthreads();
  if (t < NC) bhist[blockIdx.x * NC + t] = h[t];
}

// Exclusive scan of bhist per class across 256 chunks (in LDS), + class offsets.
// bhist[chunk][c] becomes the global base slot for class c members of chunk.
__global__ void __launch_bounds__(256) k_scan(const int* __restrict__ offsets,
                                              int* __restrict__ bhist) {
  __shared__ int lh[256 * NC];
  __shared__ int segbase[16][NC];
  int t = threadIdx.x;
  for (int u = t; u < 256 * NC; u += 256) lh[u] = bhist[u];
  __syncthreads();
  int c = t & 15, g = t >> 4;  // 16 segments of 16 chunks
  int part = 0;
#pragma unroll
  for (int b = 0; b < 16; ++b) part += lh[(g * 16 + b) * NC + c];
  segbase[g][c] = part;
  __syncthreads();
  if (t < NC) {
    int run = offsets[t];
#pragma unroll
    for (int g2 = 0; g2 < 16; ++g2) { int tmp = segbase[g2][t]; segbase[g2][t] = run; run += tmp; }
  }
  __syncthreads();
  int run = segbase[g][c];
#pragma unroll
  for (int b = 0; b < 16; ++b) {
    int idx = (g * 16 + b) * NC + c;
    int tmp = lh[idx]; lh[idx] = run; run += tmp;
  }
  __syncthreads();
  for (int u = t; u < 256 * NC; u += 256) bhist[u] = lh[u];
}

// 8 threads per point; slot = deterministic stable rank (no atomics).
__global__ void __launch_bounds__(256) k_dist(const float* __restrict__ x,
                                              const int* __restrict__ y,
                                              const float* __restrict__ centers,
                                              const float* __restrict__ csq,
                                              const int* __restrict__ bbase,
                                              float* __restrict__ Dmat) {
  __shared__ float4 cc[NC * 64];  // swizzled: (i,q) stored at i*64 + swz(q)
  __shared__ float csql[NC];
  __shared__ int labs[256];
  int t = threadIdx.x;
  const float4* cptr = (const float4*)centers;
  for (int u = t; u < NC * 64; u += 256) {
    int q = u & 63;
    int qs = (q & 0x38) | ((q & 7) ^ ((q >> 3) & 7));
    cc[(u & ~63) | qs] = cptr[u];
  }
  if (t < NC) csql[t] = csq[t];
  int chunk = blockIdx.x >> 3;  // 256-point chunk
  int sub = blockIdx.x & 7;     // 32-point group within chunk
  labs[t] = y[(chunk * 256 + t) * 3 + 2];
  __syncthreads();

  int pl = sub * 32 + (t >> 3);      // point index within chunk
  int p = chunk * 256 + pl;          // global point
  int s = t & 7;                     // dim-chunk: dims [s*32, s*32+32)
  const float4* xp = (const float4*)(x + (size_t)p * DIM) + s * 8;
  float4 xv[8];
#pragma unroll
  for (int j = 0; j < 8; ++j) xv[j] = xp[j];
  float xsq = 0.f;
#pragma unroll
  for (int j = 0; j < 8; ++j)
    xsq += xv[j].x * xv[j].x + xv[j].y * xv[j].y + xv[j].z * xv[j].z + xv[j].w * xv[j].w;

  float acc[NC];
#pragma unroll
  for (int i = 0; i < NC; ++i) acc[i] = 0.f;
#pragma unroll
  for (int i = 0; i < NC; ++i) {
#pragma unroll
    for (int j = 0; j < 8; ++j) {
      float4 cv = cc[i * 64 + s * 8 + (j ^ s)];  // element (i, q=s*8+j)
      acc[i] += xv[j].x * cv.x + xv[j].y * cv.y + xv[j].z * cv.z + xv[j].w * cv.w;
    }
  }

#pragma unroll
  for (int m = 1; m < 8; m <<= 1) {
    xsq += __shfl_xor(xsq, m);
#pragma unroll
    for (int i = 0; i < NC; ++i) acc[i] += __shfl_xor(acc[i], m);
  }

  if (s == 0) {
    int lab = labs[pl];
    int rank = 0;
    for (int q = 0; q < pl; ++q) rank += (labs[q] == lab);
    int base = bbase[chunk * NC + lab] + rank;
#pragma unroll
    for (int i = 0; i < NC; ++i) {
      float d2 = csql[i] - 2.f * acc[i] + xsq;
      Dmat[(size_t)i * NPTS + base] = sqrtf(fmaxf(d2, 0.f));
    }
  }
}

__global__ void __launch_bounds__(512) k_select(const float* __restrict__ Dmat,
                                                const int* __restrict__ gcounts,
                                                const int* __restrict__ offsets,
                                                float* __restrict__ pos_stat,
                                                float* __restrict__ neg_stat) {
  __shared__ float s[SORT_M];
  __shared__ float red[512];
  int tid = threadIdx.x;
  int b = blockIdx.x;
  int ci = b >> 4;  // center index i
  int cl = b & 15;  // class index c
  int cnt = gcounts[cl];
  int off = offsets[cl];
  const float* src = Dmat + (size_t)ci * NPTS + off;
  for (int t = tid; t < SORT_M; t += 512) s[t] = (t < cnt) ? src[t] : FLT_MAX;
  __syncthreads();

  for (int k = 2; k <= SORT_M; k <<= 1) {
    for (int j = k >> 1; j > 0; j >>= 1) {
      for (int p = tid; p < SORT_M / 2; p += 512) {
        int i = ((p & ~(j - 1)) << 1) | (p & (j - 1));
        int ixj = i | j;
        bool up = ((i & k) == 0);
        float a = s[i], bb = s[ixj];
        if ((a > bb) == up) { s[i] = bb; s[ixj] = a; }
      }
      __syncthreads();
    }
  }

  // --- neg stats: K smallest = s[0..KSEL) ---
  float part = 0.f;
  for (int t = tid; t < KSEL; t += 512) part += s[t];
  red[tid] = part; __syncthreads();
  for (int st = 256; st > 0; st >>= 1) { if (tid < st) red[tid] += red[tid + st]; __syncthreads(); }
  float mean = red[0] / (float)KSEL;
  __syncthreads();
  part = 0.f;
  for (int t = tid; t < KSEL; t += 512) { float dd = s[t] - mean; part += dd * dd; }
  red[tid] = part; __syncthreads();
  for (int st = 256; st > 0; st >>= 1) { if (tid < st) red[tid] += red[tid + st]; __syncthreads(); }
  if (tid == 0) {
    float var = red[0] / (float)(KSEL - 1);
    neg_stat[ci * 16 + cl] = mean - 1.96f * sqrtf(var);
  }

  // --- pos stats (only diagonal): K largest = s[cnt-KSEL..cnt) ---
  if (ci == cl) {
    __syncthreads();
    part = 0.f;
    for (int t = tid; t < KSEL; t += 512) part += s[cnt - KSEL + t];
    red[tid] = part; __syncthreads();
    for (int st = 256; st > 0; st >>= 1) { if (tid < st) red[tid] += red[tid + st]; __syncthreads(); }
    float pm = red[0] / (float)KSEL;
    __syncthreads();
    part = 0.f;
    for (int t = tid; t < KSEL; t += 512) { float dd = s[cnt - KSEL + t] - pm; part += dd * dd; }
    red[tid] = part; __syncthreads();
    for (int st = 256; st > 0; st >>= 1) { if (tid < st) red[tid] += red[tid + st]; __syncthreads(); }
    if (tid == 0) {
      float var = red[0] / (float)(KSEL - 1);
      pos_stat[ci] = pm + 1.96f * sqrtf(var);
    }
  }
}

__global__ void __launch_bounds__(256) k_loss(const float* __restrict__ pos_stat,
                                              const float* __restrict__ neg_stat,
                                              float* __restrict__ out) {
  __shared__ float red[256];
  int t = threadIdx.x;
  int i = t >> 4, c = t & 15;
  float v = 0.f;
  if (i != c) v = fmaxf(1.0f + pos_stat[i] - neg_stat[t], 0.f);
  red[t] = v; __syncthreads();
  for (int st = 128; st > 0; st >>= 1) { if (t < st) red[t] += red[t + st]; __syncthreads(); }
  if (t == 0) out[0] = red[0];
}

extern "C" void kernel_launch(void* const* d_in, const int* in_sizes, int n_in,
                              void* d_out, int out_size, void* d_ws, size_t ws_size,
                              hipStream_t stream) {
  const float* x = (const float*)d_in[0];
  const int* y = (const int*)d_in[1];
  float* out = (float*)d_out;
  char* ws = (char*)d_ws;

  float* sums = (float*)(ws + 0);
  int* counts = (int*)(ws + 16384);
  int* offsets = (int*)(ws + 16512);
  float* csq = (float*)(ws + 16576);
  float* pos_stat = (float*)(ws + 16640);
  float* neg_stat = (float*)(ws + 16704);
  float* centers = (float*)(ws + 17728);
  int* bhist = (int*)(ws + 34112);
  float* Dmat = (float*)(ws + 65536);

  hipMemsetAsync(ws, 0, 16512, stream);  // sums + counts
  k_accum<<<1024, 256, 0, stream>>>(x, y, sums, counts);
  k_centers<<<1, 256, 0, stream>>>(sums, counts, centers, csq, offsets);
  k_hist<<<256, 256, 0, stream>>>(y, bhist);
  k_scan<<<1, 256, 0, stream>>>(offsets, bhist);
  k_dist<<<2048, 256, 0, stream>>>(x, y, centers, csq, bhist, Dmat);
  k_select<<<256, 512, 0, stream>>>(Dmat, counts, offsets, pos_stat, neg_stat);
  k_loss<<<1, 256, 0, stream>>>(pos_stat, neg_stat, out);
}

// Round 9
// 127.554 us; speedup vs baseline: 3.0021x; 1.5963x over previous
//
#include <hip/hip_runtime.h>
#include <cfloat>
#include <cstdint>

#define NPTS 65536
#define DIM 256
#define NC 16
#define KSEL 2048
#define VMAX 4608
#define EPSV 1e-6f

// ws layout (bytes):
//     0 : float sums[16*256]   (16384)
// 16384 : int counts[16]       (64)
// 16512 : int offsets[16]      (64)
// 16576 : float csq[16]        (64)
// 16640 : float pos_stat[16]   (64)
// 16704 : float neg_stat[256]  (1024)
// 17728 : float centers[4096]  (16384)
// 34112 : int bhist[256*16]    (16384)
// 65536 : float Dmat[16*65536] (4 MB)

__global__ void __launch_bounds__(256) k_accum(const float* __restrict__ x,
                                               const int* __restrict__ y,
                                               float* __restrict__ gsums,
                                               int* __restrict__ gcounts) {
  __shared__ float lsum[NC * DIM];
  __shared__ int lcnt[NC];
  int tid = threadIdx.x;  // = dim
  for (int j = tid; j < NC * DIM; j += 256) lsum[j] = 0.f;
  if (tid < NC) lcnt[tid] = 0;
  __syncthreads();
  int n0 = blockIdx.x * 64;
  for (int r = 0; r < 64; ++r) {
    int n = n0 + r;
    int lab = y[n * 3 + 2];
    lsum[lab * DIM + tid] += x[(size_t)n * DIM + tid];
    if (tid == 0) lcnt[lab]++;
  }
  __syncthreads();
  for (int c = 0; c < NC; ++c)
    atomicAdd(&gsums[c * DIM + tid], lsum[c * DIM + tid]);
  if (tid < NC) atomicAdd(&gcounts[tid], lcnt[tid]);
}

__global__ void __launch_bounds__(256) k_centers(const float* __restrict__ gsums,
                                                 const int* __restrict__ gcounts,
                                                 float* __restrict__ centers,
                                                 float* __restrict__ csq,
                                                 int* __restrict__ offsets) {
  __shared__ float red[DIM];
  int d = threadIdx.x;
  float v[NC];
#pragma unroll
  for (int c = 0; c < NC; ++c) {
    v[c] = gsums[c * DIM + d] / (float)gcounts[c] + EPSV;
    centers[c * DIM + d] = v[c];
  }
#pragma unroll 1
  for (int c = 0; c < NC; ++c) {
    red[d] = v[c] * v[c];
    __syncthreads();
    for (int st = 128; st > 0; st >>= 1) {
      if (d < st) red[d] += red[d + st];
      __syncthreads();
    }
    if (d == 0) csq[c] = red[0];
    __syncthreads();
  }
  if (d == 0) {
    int run = 0;
    for (int c = 0; c < NC; ++c) { offsets[c] = run; run += gcounts[c]; }
  }
}

__global__ void __launch_bounds__(256) k_hist(const int* __restrict__ y,
                                              int* __restrict__ bhist) {
  __shared__ int h[NC];
  int t = threadIdx.x;
  if (t < NC) h[t] = 0;
  __syncthreads();
  int p = blockIdx.x * 256 + t;
  atomicAdd(&h[y[p * 3 + 2]], 1);
  __syncthreads();
  if (t < NC) bhist[blockIdx.x * NC + t] = h[t];
}

__global__ void __launch_bounds__(256) k_scan(const int* __restrict__ offsets,
                                              int* __restrict__ bhist) {
  __shared__ int lh[256 * NC];
  __shared__ int segbase[16][NC];
  int t = threadIdx.x;
  for (int u = t; u < 256 * NC; u += 256) lh[u] = bhist[u];
  __syncthreads();
  int c = t & 15, g = t >> 4;
  int part = 0;
#pragma unroll
  for (int b = 0; b < 16; ++b) part += lh[(g * 16 + b) * NC + c];
  segbase[g][c] = part;
  __syncthreads();
  if (t < NC) {
    int run = offsets[t];
#pragma unroll
    for (int g2 = 0; g2 < 16; ++g2) { int tmp = segbase[g2][t]; segbase[g2][t] = run; run += tmp; }
  }
  __syncthreads();
  int run = segbase[g][c];
#pragma unroll
  for (int b = 0; b < 16; ++b) {
    int idx = (g * 16 + b) * NC + c;
    int tmp = lh[idx]; lh[idx] = run; run += tmp;
  }
  __syncthreads();
  for (int u = t; u < 256 * NC; u += 256) bhist[u] = lh[u];
}

__global__ void __launch_bounds__(256) k_dist(const float* __restrict__ x,
                                              const int* __restrict__ y,
                                              const float* __restrict__ centers,
                                              const float* __restrict__ csq,
                                              const int* __restrict__ bbase,
                                              float* __restrict__ Dmat) {
  __shared__ float4 cc[NC * 64];
  __shared__ float csql[NC];
  __shared__ int labs[256];
  int t = threadIdx.x;
  const float4* cptr = (const float4*)centers;
  for (int u = t; u < NC * 64; u += 256) {
    int q = u & 63;
    int qs = (q & 0x38) | ((q & 7) ^ ((q >> 3) & 7));
    cc[(u & ~63) | qs] = cptr[u];
  }
  if (t < NC) csql[t] = csq[t];
  int chunk = blockIdx.x >> 3;
  int sub = blockIdx.x & 7;
  labs[t] = y[(chunk * 256 + t) * 3 + 2];
  __syncthreads();

  int pl = sub * 32 + (t >> 3);
  int p = chunk * 256 + pl;
  int s = t & 7;
  const float4* xp = (const float4*)(x + (size_t)p * DIM) + s * 8;
  float4 xv[8];
#pragma unroll
  for (int j = 0; j < 8; ++j) xv[j] = xp[j];
  float xsq = 0.f;
#pragma unroll
  for (int j = 0; j < 8; ++j)
    xsq += xv[j].x * xv[j].x + xv[j].y * xv[j].y + xv[j].z * xv[j].z + xv[j].w * xv[j].w;

  float acc[NC];
#pragma unroll
  for (int i = 0; i < NC; ++i) acc[i] = 0.f;
#pragma unroll
  for (int i = 0; i < NC; ++i) {
#pragma unroll
    for (int j = 0; j < 8; ++j) {
      float4 cv = cc[i * 64 + s * 8 + (j ^ s)];
      acc[i] += xv[j].x * cv.x + xv[j].y * cv.y + xv[j].z * cv.z + xv[j].w * cv.w;
    }
  }

#pragma unroll
  for (int m = 1; m < 8; m <<= 1) {
    xsq += __shfl_xor(xsq, m);
#pragma unroll
    for (int i = 0; i < NC; ++i) acc[i] += __shfl_xor(acc[i], m);
  }

  if (s == 0) {
    int lab = labs[pl];
    int rank = 0;
    for (int q = 0; q < pl; ++q) rank += (labs[q] == lab);
    int base = bbase[chunk * NC + lab] + rank;
#pragma unroll
    for (int i = 0; i < NC; ++i) {
      float d2 = csql[i] - 2.f * acc[i] + xsq;
      Dmat[(size_t)i * NPTS + base] = sqrtf(fmaxf(d2, 0.f));
    }
  }
}

// Radix-select (exact K-th order statistic via 11+11+10-bit LDS histograms),
// then two-pass mean/var over {key < T} + exact-tie correction. No sort.
// Off-diagonal blocks: K smallest (neg). Diagonal: K largest (pos, key=~u).
__global__ void __launch_bounds__(512) k_select(const float* __restrict__ Dmat,
                                                const int* __restrict__ gcounts,
                                                const int* __restrict__ offsets,
                                                float* __restrict__ pos_stat,
                                                float* __restrict__ neg_stat) {
  __shared__ unsigned int keys[VMAX];
  __shared__ int hist[2048];
  __shared__ int sc[512];
  __shared__ float fred[512];
  __shared__ int bsel[2];  // selected bin, new target
  int tid = threadIdx.x;
  int b = blockIdx.x;
  int ci = b >> 4, cl = b & 15;
  bool largest = (ci == cl);
  int cnt = gcounts[cl];
  if (cnt > VMAX) cnt = VMAX;
  int off = offsets[cl];
  const float* src = Dmat + (size_t)ci * NPTS + off;
  unsigned int inv = largest ? 0xFFFFFFFFu : 0u;
  for (int t = tid; t < cnt; t += 512) keys[t] = __float_as_uint(src[t]) ^ inv;
  __syncthreads();

  int target = KSEL;
  unsigned int pfx = 0;

  // ---- Level A: bits [21,32), 2048 bins ----
  for (int u = tid; u < 2048; u += 512) hist[u] = 0;
  __syncthreads();
  for (int t = tid; t < cnt; t += 512) atomicAdd(&hist[keys[t] >> 21], 1);
  __syncthreads();
  {
    int segsum = 0;
#pragma unroll
    for (int j = 0; j < 4; ++j) segsum += hist[tid * 4 + j];
    sc[tid] = segsum; __syncthreads();
    for (int ofs = 1; ofs < 512; ofs <<= 1) {
      int v = (tid >= ofs) ? sc[tid - ofs] : 0; __syncthreads();
      sc[tid] += v; __syncthreads();
    }
    int incl = sc[tid], excl = incl - segsum;
    if (excl < target && target <= incl) {
      int run = excl;
      for (int j = 0; j < 4; ++j) {
        int h = hist[tid * 4 + j];
        if (run < target && target <= run + h) { bsel[0] = tid * 4 + j; bsel[1] = target - run; }
        run += h;
      }
    }
    __syncthreads();
    pfx = ((unsigned int)bsel[0]) << 21; target = bsel[1];
  }
  __syncthreads();

  // ---- Level B: bits [10,21), 2048 bins, filter top-11 == pfx ----
  for (int u = tid; u < 2048; u += 512) hist[u] = 0;
  __syncthreads();
  for (int t = tid; t < cnt; t += 512) {
    unsigned int k = keys[t];
    if ((k >> 21) == (pfx >> 21)) atomicAdd(&hist[(k >> 10) & 0x7FF], 1);
  }
  __syncthreads();
  {
    int segsum = 0;
#pragma unroll
    for (int j = 0; j < 4; ++j) segsum += hist[tid * 4 + j];
    sc[tid] = segsum; __syncthreads();
    for (int ofs = 1; ofs < 512; ofs <<= 1) {
      int v = (tid >= ofs) ? sc[tid - ofs] : 0; __syncthreads();
      sc[tid] += v; __syncthreads();
    }
    int incl = sc[tid], excl = incl - segsum;
    if (excl < target && target <= incl) {
      int run = excl;
      for (int j = 0; j < 4; ++j) {
        int h = hist[tid * 4 + j];
        if (run < target && target <= run + h) { bsel[0] = tid * 4 + j; bsel[1] = target - run; }
        run += h;
      }
    }
    __syncthreads();
    pfx |= ((unsigned int)bsel[0]) << 10; target = bsel[1];
  }
  __syncthreads();

  // ---- Level C: bits [0,10), 1024 bins, filter top-22 == pfx ----
  for (int u = tid; u < 1024; u += 512) hist[u] = 0;
  __syncthreads();
  for (int t = tid; t < cnt; t += 512) {
    unsigned int k = keys[t];
    if ((k >> 10) == (pfx >> 10)) atomicAdd(&hist[k & 0x3FF], 1);
  }
  __syncthreads();
  {
    int segsum = hist[tid * 2] + hist[tid * 2 + 1];
    sc[tid] = segsum; __syncthreads();
    for (int ofs = 1; ofs < 512; ofs <<= 1) {
      int v = (tid >= ofs) ? sc[tid - ofs] : 0; __syncthreads();
      sc[tid] += v; __syncthreads();
    }
    int incl = sc[tid], excl = incl - segsum;
    if (excl < target && target <= incl) {
      int run = excl;
      for (int j = 0; j < 2; ++j) {
        int h = hist[tid * 2 + j];
        if (run < target && target <= run + h) { bsel[0] = tid * 2 + j; }
        run += h;
      }
    }
    __syncthreads();
  }
  unsigned int T = pfx | (unsigned int)bsel[0];
  float fT = __uint_as_float(T ^ inv);
  __syncthreads();

  // ---- pass 1: n_less, sum_less ----
  int nl = 0; float sl = 0.f;
  for (int t = tid; t < cnt; t += 512) {
    unsigned int k = keys[t];
    if (k < T) { nl++; sl += __uint_as_float(k ^ inv); }
  }
  sc[tid] = nl; fred[tid] = sl; __syncthreads();
  for (int st = 256; st > 0; st >>= 1) {
    if (tid < st) { sc[tid] += sc[tid + st]; fred[tid] += fred[tid + st]; }
    __syncthreads();
  }
  int n_less = sc[0];
  float mean = (fred[0] + (float)(KSEL - n_less) * fT) / (float)KSEL;
  __syncthreads();

  // ---- pass 2: variance (two-pass, exact tie handling) ----
  float sv = 0.f;
  for (int t = tid; t < cnt; t += 512) {
    unsigned int k = keys[t];
    if (k < T) { float d = __uint_as_float(k ^ inv) - mean; sv += d * d; }
  }
  fred[tid] = sv; __syncthreads();
  for (int st = 256; st > 0; st >>= 1) {
    if (tid < st) fred[tid] += fred[tid + st];
    __syncthreads();
  }
  if (tid == 0) {
    float dT = fT - mean;
    float var = (fred[0] + (float)(KSEL - n_less) * dT * dT) / (float)(KSEL - 1);
    if (largest) pos_stat[ci] = mean + 1.96f * sqrtf(var);
    else neg_stat[ci * 16 + cl] = mean - 1.96f * sqrtf(var);
  }
}

__global__ void __launch_bounds__(256) k_loss(const float* __restrict__ pos_stat,
                                              const float* __restrict__ neg_stat,
                                              float* __restrict__ out) {
  __shared__ float red[256];
  int t = threadIdx.x;
  int i = t >> 4, c = t & 15;
  float v = 0.f;
  if (i != c) v = fmaxf(1.0f + pos_stat[i] - neg_stat[t], 0.f);
  red[t] = v; __syncthreads();
  for (int st = 128; st > 0; st >>= 1) { if (t < st) red[t] += red[t + st]; __syncthreads(); }
  if (t == 0) out[0] = red[0];
}

extern "C" void kernel_launch(void* const* d_in, const int* in_sizes, int n_in,
                              void* d_out, int out_size, void* d_ws, size_t ws_size,
                              hipStream_t stream) {
  const float* x = (const float*)d_in[0];
  const int* y = (const int*)d_in[1];
  float* out = (float*)d_out;
  char* ws = (char*)d_ws;

  float* sums = (float*)(ws + 0);
  int* counts = (int*)(ws + 16384);
  int* offsets = (int*)(ws + 16512);
  float* csq = (float*)(ws + 16576);
  float* pos_stat = (float*)(ws + 16640);
  float* neg_stat = (float*)(ws + 16704);
  float* centers = (float*)(ws + 17728);
  int* bhist = (int*)(ws + 34112);
  float* Dmat = (float*)(ws + 65536);

  hipMemsetAsync(ws, 0, 16512, stream);  // sums + counts
  k_accum<<<1024, 256, 0, stream>>>(x, y, sums, counts);
  k_centers<<<1, 256, 0, stream>>>(sums, counts, centers, csq, offsets);
  k_hist<<<256, 256, 0, stream>>>(y, bhist);
  k_scan<<<1, 256, 0, stream>>>(offsets, bhist);
  k_dist<<<2048, 256, 0, stream>>>(x, y, centers, csq, bhist, Dmat);
  k_select<<<256, 512, 0, stream>>>(Dmat, counts, offsets, pos_stat, neg_stat);
  k_loss<<<1, 256, 0, stream>>>(pos_stat, neg_stat, out);
}